// Round 1
// 182.999 us; speedup vs baseline: 1.0019x; 1.0019x over previous
//
#include <hip/hip_runtime.h>

#define ROWS 1048576
#define BINS 17
#define RPB 128                 // rows per block = threads per block (2 waves)
#define NBLK (ROWS / RPB)       // 8192 blocks
#define NPART (2 * NBLK)        // 16384 partials per quantity (one per wave)
#define GPB (RPB / 4)           // 32 conv groups per block
#define CONV_N 33               // 2*BINS - 1
#define L2E 1.442695040888963f
#define LN2 0.6931471805599453f

// 2-wave blocks: WG-slot limit (16 WG/CU) capped the 64-thread version at 16
// waves/CU (measured 35% occ). 17.4 KB LDS -> 9 blocks/CU x 2 waves = 18-wave
// cap. VALU diet: one-pass variance, exp2-native softmax chain with the
// normalization scale folded into the exp2 argument ((x-xmax)*s — mean shift
// cancels under the affine normalize), merged KL (no 4th exp loop), target
// exps cached in regs for the publish, v_rcp everywhere, and the 289-FMA conv
// packed into ONE full wave (64 tasks = 64 lanes) instead of half of each.
template <bool PART>
__global__ __launch_bounds__(128, 4) void kd_main(
    const float* __restrict__ pred,
    const float* __restrict__ soft,
    const float* __restrict__ weight,
    float* __restrict__ out,
    float* __restrict__ ws)
{
    __shared__ float sA[RPB * BINS];  // pred tile -> target softmax publish
    __shared__ float sB[RPB * BINS];  // soft tile -> ratio restage
    const int tid = threadIdx.x;
    const long long base = (long long)blockIdx.x * (RPB * BINS);

    // ---- coalesced staging: 544 float4 per tile, base 8704B-aligned ----
    const float4* p4 = reinterpret_cast<const float4*>(pred + base);
    const float4* q4 = reinterpret_cast<const float4*>(soft + base);
    float4* a4 = reinterpret_cast<float4*>(sA);
    float4* b4 = reinterpret_cast<float4*>(sB);
#pragma unroll
    for (int k = 0; k < 4; ++k) {
        a4[k * RPB + tid] = p4[k * RPB + tid];
        b4[k * RPB + tid] = q4[k * RPB + tid];
    }
    if (tid < 32) {
        a4[512 + tid] = p4[512 + tid];
        b4[512 + tid] = q4[512 + tid];
    }
    const float w = weight[blockIdx.x * RPB + tid];
    __syncthreads();

    // ---- per-row math (row = tid); stride 17 (odd) -> 2-way alias, free ----
    float x[BINS], y[BINS];
    float sx = 0.f, sy = 0.f, sxx = 0.f, syy = 0.f;
    float xmx = -1e30f, ymx = -1e30f;
#pragma unroll
    for (int j = 0; j < BINS; ++j) {
        x[j] = sA[tid * BINS + j];
        y[j] = sB[tid * BINS + j];
        sx += x[j]; sxx = fmaf(x[j], x[j], sxx); xmx = fmaxf(xmx, x[j]);
        sy += y[j]; syy = fmaf(y[j], y[j], syy); ymx = fmaxf(ymx, y[j]);
    }
    const float mx = sx * (1.0f / BINS);
    const float my = sy * (1.0f / BINS);
    // one-pass ddof=1 variance; clamp vs tiny negative cancellation
    const float vx = fmaxf(fmaf(-sx, mx, sxx), 0.f) * (1.0f / (BINS - 1));
    const float vy = fmaxf(fmaf(-sy, my, syy), 0.f) * (1.0f / (BINS - 1));
    // scale = (1/T) * log2(e) / (eps + std); exp2 arg = (v - vmax) * scale
    const float sxl = (0.1f * L2E) *
        __builtin_amdgcn_rcpf(1e-7f + __builtin_amdgcn_sqrtf(vx));
    const float syl = (0.1f * L2E) *
        __builtin_amdgcn_rcpf(1e-7f + __builtin_amdgcn_sqrtf(vy));
    const float cA = -xmx * sxl;
    const float cB = -ymx * syl;
    const float cT = -ymx * L2E;      // raw-y softmax, exp2 units

    float et[BINS];
    float sea = 0.f, seb = 0.f, ts = 0.f, sdb = 0.f;
#pragma unroll
    for (int j = 0; j < BINS; ++j) {
        const float aj = fmaf(x[j], sxl, cA);          // log2 student logits
        const float bj = fmaf(y[j], syl, cB);          // log2 teacher logits
        const float ea = exp2f(aj);                    // v_exp_f32, native
        const float eb = exp2f(bj);
        const float tv = exp2f(fmaf(y[j], L2E, cT));
        sea += ea; seb += eb; ts += tv;
        sdb = fmaf(eb, bj - aj, sdb);                  // sum eb*(bj-aj), log2
        et[j] = tv;                                    // cache for publish
    }
    // KL = ln2 * ( sum(eb*(bj-aj))/seb + log2(sea) - log2(seb) )
    const float kl = LN2 * (sdb * __builtin_amdgcn_rcpf(seb)
                            + (__log2f(sea) - __log2f(seb)));
    const float invts = __builtin_amdgcn_rcpf(ts);

    // target softmax -> overwrite OWN row of sA (no cross-thread hazard)
#pragma unroll
    for (int j = 0; j < BINS; ++j)
        sA[tid * BINS + j] = et[j] * invts;

    // ---- per-wave reduce kl & weight; one partial pair per wave ----
    float k2 = kl, w2 = w;
#pragma unroll
    for (int off = 32; off >= 1; off >>= 1) {
        k2 += __shfl_down(k2, off, 64);
        w2 += __shfl_down(w2, off, 64);
    }
    if ((tid & 63) == 0) {
        const int wv = tid >> 6;
        if (PART) {
            ws[2 * blockIdx.x + wv]         = k2;
            ws[NPART + 2 * blockIdx.x + wv] = w2;
        } else {
            atomicAdd(&ws[0], k2);
            atomicAdd(&ws[1], w2);
        }
    }

    __syncthreads();  // publish softmax rows to conv wave

    float* sR = sB;  // soft tile dead; reuse as ratio staging (1056 floats)

    // ---- conv: ONE full wave, 64 tasks. even lane: left*right rows
    //      (4g+2,3); odd: top*bottom rows (4g+0,1). Pair = 34 contiguous
    //      floats, 8B-aligned; 4-way max bank alias on b64 reads. ----
    if (tid < 64) {
        const int g = tid >> 1;
        const int R = 4 * g + ((tid & 1) ? 0 : 2);
        float f[2 * BINS];
        const float2* pr = reinterpret_cast<const float2*>(&sA[R * BINS]);
#pragma unroll
        for (int i = 0; i < BINS; ++i) {
            const float2 v = pr[i];
            f[2 * i] = v.x; f[2 * i + 1] = v.y;
        }
        float accv[CONV_N];
#pragma unroll
        for (int j = 0; j < CONV_N; ++j) accv[j] = 0.f;
#pragma unroll
        for (int k = 0; k < BINS; ++k)
#pragma unroll
            for (int m = 0; m < BINS; ++m)
                accv[k + m] = fmaf(f[k], f[BINS + m], accv[k + m]);

        // adjacent-lane exchange: even lane = slr, odd lane = stb
#pragma unroll
        for (int j = 0; j < CONV_N; ++j) {
            const float o = __shfl_down(accv[j], 1, 64);
            if ((tid & 1) == 0)
                sR[g * CONV_N + j] = accv[j] *
                    __builtin_amdgcn_rcpf(o + 1e-8f);
        }
    }
    __syncthreads();

    // ---- coalesced store of the 1056 ratio floats ----
    const long long ob = 1 + (long long)blockIdx.x * (GPB * CONV_N);
#pragma unroll
    for (int i = 0; i < 8; ++i)
        out[ob + i * RPB + tid] = sR[i * RPB + tid];
    if (tid < 32) out[ob + 1024 + tid] = sR[1024 + tid];
}

// PART=true: reduce 2*16384 partials; else just combine the two atomics.
template <bool PART>
__global__ __launch_bounds__(1024) void kd_reduce(
    const float* __restrict__ ws, float* __restrict__ out)
{
    if (!PART) {
        if (threadIdx.x == 0)
            out[0] = 100.0f * (ws[0] * (1.0f / ROWS)) * (ws[1] * (1.0f / ROWS));
        return;
    }
    __shared__ float red[32];
    const int tid = threadIdx.x;
    const float4* k4 = reinterpret_cast<const float4*>(ws);           // 4096 f4
    const float4* w4 = reinterpret_cast<const float4*>(ws + NPART);   // 4096 f4
    float ks = 0.f, wsum = 0.f;
#pragma unroll
    for (int i = 0; i < 4; ++i) {
        const float4 a = k4[i * 1024 + tid];
        const float4 b = w4[i * 1024 + tid];
        ks += (a.x + a.y) + (a.z + a.w);
        wsum += (b.x + b.y) + (b.z + b.w);
    }
#pragma unroll
    for (int off = 32; off >= 1; off >>= 1) {
        ks += __shfl_down(ks, off, 64);
        wsum += __shfl_down(wsum, off, 64);
    }
    if ((tid & 63) == 0) {
        red[(tid >> 6) * 2 + 0] = ks;
        red[(tid >> 6) * 2 + 1] = wsum;
    }
    __syncthreads();
    if (tid == 0) {
        float K = 0.f, W = 0.f;
#pragma unroll
        for (int i = 0; i < 16; ++i) { K += red[2 * i]; W += red[2 * i + 1]; }
        out[0] = 100.0f * (K * (1.0f / ROWS)) * (W * (1.0f / ROWS));
    }
}

extern "C" void kernel_launch(void* const* d_in, const int* in_sizes, int n_in,
                              void* d_out, int out_size, void* d_ws, size_t ws_size,
                              hipStream_t stream)
{
    const float* pred   = (const float*)d_in[0];
    const float* soft   = (const float*)d_in[1];
    const float* weight = (const float*)d_in[2];
    float* out = (float*)d_out;
    float* ws  = (float*)d_ws;

    if (ws_size >= (size_t)(2 * NPART) * sizeof(float)) {
        kd_main<true><<<NBLK, RPB, 0, stream>>>(pred, soft, weight, out, ws);
        kd_reduce<true><<<1, 1024, 0, stream>>>(ws, out);
    } else {
        hipMemsetAsync(ws, 0, 2 * sizeof(float), stream);
        kd_main<false><<<NBLK, RPB, 0, stream>>>(pred, soft, weight, out, ws);
        kd_reduce<false><<<1, 1024, 0, stream>>>(ws, out);
    }
}

// Round 3
// 181.759 us; speedup vs baseline: 1.0088x; 1.0068x over previous
//
#include <hip/hip_runtime.h>

#define ROWS 1048576
#define BINS 17
#define RPB 128                 // rows per block = threads per block (2 waves)
#define NBLK (ROWS / RPB)       // 8192 blocks
#define NPART (2 * NBLK)        // 16384 partials per quantity (one per wave)
#define GPB (RPB / 4)           // 32 conv groups per block
#define CONV_N 33               // 2*BINS - 1
#define L2E 1.442695040888963f
#define LN2 0.6931471805599453f

// Round-2 restructure: NO input staging. Each thread owns one contiguous
// 68-B row of pred and soft -> load straight into registers (17 scalar
// dword loads each; same HBM bytes, L1 absorbs the intra-wave scatter) and
// drop the global->VGPR->LDS->barrier chain entirely. LDS is only the
// target-softmax publish (2176 f) + invts[128] = 9.2 KB -> residency cap
// rises from 9 blocks (17.4 KB) to the 16-WG slot limit = 32 waves/CU.
// __launch_bounds__(128,8) pins VGPRs <= 64 so the 8-wave/SIMD cap holds
// (live set ~55: x[17]+y[17]+scalars). Softmax normalization is deferred to
// the conv lanes (multiply by sI[row] at f[] load) so no et[] cache and no
// second publish pass. Ratio staging aliases the publish buffer: the conv
// wave's ds_reads all precede its ds_writes in program order (single wave,
// data-dependent) so no barrier is needed for the overlay.
template <bool PART>
__global__ __launch_bounds__(128, 8) void kd_main(
    const float* __restrict__ pred,
    const float* __restrict__ soft,
    const float* __restrict__ weight,
    float* __restrict__ out,
    float* __restrict__ ws)
{
    __shared__ float sA[RPB * BINS + RPB];  // et publish (2176) + invts (128)
    float* sI = sA + RPB * BINS;
    const int tid = threadIdx.x;

    // ---- direct per-row register loads (17+17 dwords, no barrier) ----
    const long long rowbase = ((long long)blockIdx.x * RPB + tid) * BINS;
    const float* px = pred + rowbase;
    const float* py = soft + rowbase;
    float x[BINS], y[BINS];
#pragma unroll
    for (int j = 0; j < BINS; ++j) x[j] = px[j];
#pragma unroll
    for (int j = 0; j < BINS; ++j) y[j] = py[j];
    const float w = weight[blockIdx.x * RPB + tid];

    // ---- one-pass stats ----
    float sx = 0.f, sy = 0.f, sxx = 0.f, syy = 0.f;
    float xmx = -1e30f, ymx = -1e30f;
#pragma unroll
    for (int j = 0; j < BINS; ++j) {
        sx += x[j]; sxx = fmaf(x[j], x[j], sxx); xmx = fmaxf(xmx, x[j]);
        sy += y[j]; syy = fmaf(y[j], y[j], syy); ymx = fmaxf(ymx, y[j]);
    }
    const float mx = sx * (1.0f / BINS);
    const float my = sy * (1.0f / BINS);
    const float vx = fmaxf(fmaf(-sx, mx, sxx), 0.f) * (1.0f / (BINS - 1));
    const float vy = fmaxf(fmaf(-sy, my, syy), 0.f) * (1.0f / (BINS - 1));
    // scale = (1/T) * log2(e) / (eps + std); exp2 arg = (v - vmax) * scale
    const float sxl = (0.1f * L2E) *
        __builtin_amdgcn_rcpf(1e-7f + __builtin_amdgcn_sqrtf(vx));
    const float syl = (0.1f * L2E) *
        __builtin_amdgcn_rcpf(1e-7f + __builtin_amdgcn_sqrtf(vy));
    const float cA = -xmx * sxl;
    const float cB = -ymx * syl;
    const float cT = -ymx * L2E;      // raw-y softmax, exp2 units

    // ---- fused exp pass; publish UNNORMALIZED target exps to own row ----
    float sea = 0.f, seb = 0.f, ts = 0.f, sdb = 0.f;
#pragma unroll
    for (int j = 0; j < BINS; ++j) {
        const float aj = fmaf(x[j], sxl, cA);          // log2 student logits
        const float bj = fmaf(y[j], syl, cB);          // log2 teacher logits
        const float ea = exp2f(aj);
        const float eb = exp2f(bj);
        const float tv = exp2f(fmaf(y[j], L2E, cT));
        sea += ea; seb += eb; ts += tv;
        sdb = fmaf(eb, bj - aj, sdb);                  // sum eb*(bj-aj), log2
        sA[tid * BINS + j] = tv;                       // own row, no hazard
    }
    // KL = ln2 * ( sum(eb*(bj-aj))/seb + log2(sea) - log2(seb) )
    const float kl = LN2 * (sdb * __builtin_amdgcn_rcpf(seb)
                            + (__log2f(sea) - __log2f(seb)));
    sI[tid] = __builtin_amdgcn_rcpf(ts);               // deferred normalizer

    // ---- per-wave reduce kl & weight; one partial pair per wave ----
    float k2 = kl, w2 = w;
#pragma unroll
    for (int off = 32; off >= 1; off >>= 1) {
        k2 += __shfl_down(k2, off, 64);
        w2 += __shfl_down(w2, off, 64);
    }
    if ((tid & 63) == 0) {
        const int wv = tid >> 6;
        if (PART) {
            ws[2 * blockIdx.x + wv]         = k2;
            ws[NPART + 2 * blockIdx.x + wv] = w2;
        } else {
            atomicAdd(&ws[0], k2);
            atomicAdd(&ws[1], w2);
        }
    }

    __syncthreads();  // publish softmax rows + invts to conv wave

    float* sR = sA;  // ratio staging overlays publish buffer (see header)

    // ---- conv: ONE full wave, 64 tasks. even lane: left*right rows
    //      (4g+2,3); odd: top*bottom rows (4g+0,1). Pair = 34 contiguous
    //      floats, 8B-aligned; normalization folded in at load. ----
    if (tid < 64) {
        const int g = tid >> 1;
        const int R = 4 * g + ((tid & 1) ? 0 : 2);
        const float s0 = sI[R], s1 = sI[R + 1];
        float f[2 * BINS];
        const float2* pr = reinterpret_cast<const float2*>(&sA[R * BINS]);
#pragma unroll
        for (int i = 0; i < BINS; ++i) {
            const float2 v = pr[i];
            f[2 * i]     = v.x * (2 * i     < BINS ? s0 : s1);
            f[2 * i + 1] = v.y * (2 * i + 1 < BINS ? s0 : s1);
        }
        float accv[CONV_N];
#pragma unroll
        for (int j = 0; j < CONV_N; ++j) accv[j] = 0.f;
#pragma unroll
        for (int k = 0; k < BINS; ++k)
#pragma unroll
            for (int m = 0; m < BINS; ++m)
                accv[k + m] = fmaf(f[k], f[BINS + m], accv[k + m]);

        // adjacent-lane exchange: even lane = slr, odd lane = stb
#pragma unroll
        for (int j = 0; j < CONV_N; ++j) {
            const float o = __shfl_down(accv[j], 1, 64);
            if ((tid & 1) == 0)
                sR[g * CONV_N + j] = accv[j] *
                    __builtin_amdgcn_rcpf(o + 1e-8f);
        }
    }
    __syncthreads();

    // ---- coalesced store of the 1056 ratio floats ----
    const long long ob = 1 + (long long)blockIdx.x * (GPB * CONV_N);
#pragma unroll
    for (int i = 0; i < 8; ++i)
        out[ob + i * RPB + tid] = sR[i * RPB + tid];
    if (tid < 32) out[ob + 1024 + tid] = sR[1024 + tid];
}

// PART=true: reduce 2*16384 partials; else just combine the two atomics.
template <bool PART>
__global__ __launch_bounds__(1024) void kd_reduce(
    const float* __restrict__ ws, float* __restrict__ out)
{
    if (!PART) {
        if (threadIdx.x == 0)
            out[0] = 100.0f * (ws[0] * (1.0f / ROWS)) * (ws[1] * (1.0f / ROWS));
        return;
    }
    __shared__ float red[32];
    const int tid = threadIdx.x;
    const float4* k4 = reinterpret_cast<const float4*>(ws);           // 4096 f4
    const float4* w4 = reinterpret_cast<const float4*>(ws + NPART);   // 4096 f4
    float ks = 0.f, wsum = 0.f;
#pragma unroll
    for (int i = 0; i < 4; ++i) {
        const float4 a = k4[i * 1024 + tid];
        const float4 b = w4[i * 1024 + tid];
        ks += (a.x + a.y) + (a.z + a.w);
        wsum += (b.x + b.y) + (b.z + b.w);
    }
#pragma unroll
    for (int off = 32; off >= 1; off >>= 1) {
        ks += __shfl_down(ks, off, 64);
        wsum += __shfl_down(wsum, off, 64);
    }
    if ((tid & 63) == 0) {
        red[(tid >> 6) * 2 + 0] = ks;
        red[(tid >> 6) * 2 + 1] = wsum;
    }
    __syncthreads();
    if (tid == 0) {
        float K = 0.f, W = 0.f;
#pragma unroll
        for (int i = 0; i < 16; ++i) { K += red[2 * i]; W += red[2 * i + 1]; }
        out[0] = 100.0f * (K * (1.0f / ROWS)) * (W * (1.0f / ROWS));
    }
}

extern "C" void kernel_launch(void* const* d_in, const int* in_sizes, int n_in,
                              void* d_out, int out_size, void* d_ws, size_t ws_size,
                              hipStream_t stream)
{
    const float* pred   = (const float*)d_in[0];
    const float* soft   = (const float*)d_in[1];
    const float* weight = (const float*)d_in[2];
    float* out = (float*)d_out;
    float* ws  = (float*)d_ws;

    if (ws_size >= (size_t)(2 * NPART) * sizeof(float)) {
        kd_main<true><<<NBLK, RPB, 0, stream>>>(pred, soft, weight, out, ws);
        kd_reduce<true><<<1, 1024, 0, stream>>>(ws, out);
    } else {
        hipMemsetAsync(ws, 0, 2 * sizeof(float), stream);
        kd_main<false><<<NBLK, RPB, 0, stream>>>(pred, soft, weight, out, ws);
        kd_reduce<false><<<1, 1024, 0, stream>>>(ws, out);
    }
}